// Round 15
// baseline (48.369 us; speedup 1.0000x reference)
//
#include <hip/hip_runtime.h>

#define N_TOKS 1024
#define N_ATOMS 4096
#define CS 384
#define CZ 128
#define CATOM 128
#define CPAIR 16
#define NQ 32
#define NK 128
#define NBLK 128           // N_ATOMS / NQ
#define KOFF (-48)         // NQ/2 - NK/2
#define KSEG 32
#define NSEG (NK / KSEG)   // 4
#define NTILE (NBLK * NSEG) // 512 z-tiles
#define NB_A 256
#define NB_S 1024          // stream blocks
#define MAXP 1024          // worst-case pairs per tile (32x32)
#define MAPSTRIDE 68       // ints per tile: [0]=uk, [1..32]=qmap, [33..64]=kmap, [65]=validmask
#define LN_EPS 1e-5f

struct alignas(16) SMemB {
    int ends[N_TOKS];
    int tokq[NQ]; int tokk[KSEG];
    int qmap[NQ]; int kmap[KSEG];
    int uqtok[NQ]; int uktok[KSEG];
    int uqk[2];
    int wsum[4];
    int vmask;
};

union alignas(16) SMemS {
    struct {                        // stream role (~0.6 KB)
        int kmap_l[NK];
        int qmap_l[4];
        int uk_l[4];
        int vm_l[4];
    } s;
    struct {                        // A role (~20 KB)
        int ends[N_TOKS];           // 4 KB
        float xh[CS][4];            // 6 KB
        float sacc[4][4][CATOM];    // 8 KB (4 c-chunks)
        float s_l[4][CATOM];        // 2 KB
        int wsum[4];
    } a;
};

// shuffle-based scan of na[0..1023] -> inclusive ends[] in LDS (2 barriers)
__device__ __forceinline__ void scan_ends(const int* __restrict__ na, int* ends, int* wsum, int t) {
    int4 v = ((const int4*)na)[t];
    int e0 = v.x, e1 = e0 + v.y, e2 = e1 + v.z, e3 = e2 + v.w;
    int s = e3;
    int lane = t & 63, w = t >> 6;
    #pragma unroll
    for (int off = 1; off < 64; off <<= 1) {
        int u = __shfl_up(s, off);
        if (lane >= off) s += u;
    }
    if (lane == 63) wsum[w] = s;
    __syncthreads();
    int wbase = 0;
    #pragma unroll
    for (int i = 0; i < 4; i++) wbase += (i < w) ? wsum[i] : 0;
    int base = wbase + s - e3;
    ends[4 * t + 0] = base + e0;
    ends[4 * t + 1] = base + e1;
    ends[4 * t + 2] = base + e2;
    ends[4 * t + 3] = base + e3;
    __syncthreads();
}

__device__ __forceinline__ int bsearch_tok(const int* ends, int a) {
    int lo = 0, hi = N_TOKS - 1;
    while (lo < hi) { int mid = (lo + hi) >> 1; if (ends[mid] > a) hi = mid; else lo = mid + 1; }
    return lo;
}

// ============ k_pre: 512 pure-B blocks: z at unique pairs -> z_ws, maps -> maps_ws ============
__global__ __launch_bounds__(256) void k_pre(
        const int* __restrict__ na,
        const float* __restrict__ zij, const float* __restrict__ lnzw,
        const float* __restrict__ Wz, const float* __restrict__ bz,
        float* __restrict__ z_ws, int* __restrict__ maps_ws) {
    __shared__ SMemB sm;
    int t = threadIdx.x;
    int x = blockIdx.x;
    int blk = x >> 2, kseg = x & 3;
    scan_ends(na, sm.ends, sm.wsum, t);

    if (t < NQ) {
        sm.tokq[t] = bsearch_tok(sm.ends, blk * NQ + t);
    } else if (t >= 64 && t < 64 + KSEG) {
        int kk = t - 64;
        int kg = blk * NQ + KOFF + kseg * KSEG + kk;
        unsigned long long vm = __ballot(kg >= 0 && kg < N_ATOMS);
        if (kk == 0) sm.vmask = (int)(vm & 0xffffffffull);
        sm.tokk[kk] = bsearch_tok(sm.ends, min(max(kg, 0), N_ATOMS - 1));
    }
    __syncthreads();

    // wave-parallel dedup via ballot (wave 0: q side, wave 1: k side)
    if (t < NQ) {
        int tq = sm.tokq[t];
        bool head = (t == 0) || (tq != sm.tokq[t - 1]);
        unsigned long long m = __ballot(head);
        int rank = (int)__popcll(m & ((2ull << t) - 1)) - 1;
        sm.qmap[t] = rank;
        if (head) sm.uqtok[rank] = tq;
        if (t == 0) sm.uqk[0] = (int)__popcll(m);
    } else if (t >= 64 && t < 64 + KSEG) {
        int lane = t - 64;
        int tk = sm.tokk[lane];
        bool head = (lane == 0) || (tk != sm.tokk[lane - 1]);
        unsigned long long m = __ballot(head);
        int rank = (int)__popcll(m & ((2ull << lane) - 1)) - 1;
        sm.kmap[lane] = rank;
        if (head) sm.uktok[rank] = tk;
        if (lane == 0) sm.uqk[1] = (int)__popcll(m);
    }
    __syncthreads();
    int uq = sm.uqk[0], uk = sm.uqk[1];
    int npairs = uq * uk;      // typical ~72, worst 1024

    // write maps
    int* mp = maps_ws + x * MAPSTRIDE;
    if (t < NQ) mp[1 + t] = sm.qmap[t];
    else if (t >= 64 && t < 64 + KSEG) mp[33 + (t - 64)] = sm.kmap[t - 64];
    else if (t == 96) mp[0] = uk;
    else if (t == 97) mp[65] = sm.vmask;

    // z at unique pairs, 1 lane per pair (register-lean, proven body) -> z_ws
    for (int p = t; p < npairs; p += 256) {
        int qi = p / uk, ki = p - qi * uk;
        int tq = sm.uqtok[qi], tk = sm.uktok[ki];
        const float* row = zij + ((size_t)tq * N_TOKS + tk) * CZ;
        float sum = 0.f, sq = 0.f;
        for (int c4 = 0; c4 < CZ / 4; c4++) {
            float4 v = *(const float4*)(row + c4 * 4);
            sum += v.x + v.y + v.z + v.w;
            sq  += v.x * v.x + v.y * v.y + v.z * v.z + v.w * v.w;
        }
        float mu = sum * (1.f / CZ);
        float rstd = rsqrtf(sq * (1.f / CZ) - mu * mu + LN_EPS);
        float acc[CPAIR];
        #pragma unroll
        for (int d = 0; d < CPAIR; d++) acc[d] = bz[d];
        for (int c4 = 0; c4 < CZ / 4; c4++) {
            float4 v = *(const float4*)(row + c4 * 4);
            float xs4[4] = {v.x, v.y, v.z, v.w};
            #pragma unroll
            for (int j = 0; j < 4; j++) {
                int c = c4 * 4 + j;
                float xv = (xs4[j] - mu) * rstd * lnzw[c];
                const float* wrow = Wz + c * CPAIR;
                #pragma unroll
                for (int d = 0; d < CPAIR; d++) acc[d] += xv * wrow[d];
            }
        }
        float4* zt = (float4*)(z_ws + ((size_t)x * MAXP + p) * CPAIR);
        zt[0] = make_float4(acc[0], acc[1], acc[2], acc[3]);
        zt[1] = make_float4(acc[4], acc[5], acc[6], acc[7]);
        zt[2] = make_float4(acc[8], acc[9], acc[10], acc[11]);
        zt[3] = make_float4(acc[12], acc[13], acc[14], acc[15]);
    }
}

// ============ k_stream: 1024 stream blocks + 256 A-role blocks ============
__global__ __launch_bounds__(256) void k_stream(
        const float* __restrict__ z_ws, const int* __restrict__ maps_ws,
        const float* __restrict__ plm, float* __restrict__ plm_out,
        const int* __restrict__ na, const float* __restrict__ si,
        const float* __restrict__ lnw, const float* __restrict__ Ws,
        const float* __restrict__ bs, const float* __restrict__ mask,
        const float* __restrict__ cl, const float* __restrict__ rl,
        const float* __restrict__ Wr, const float* __restrict__ br,
        float* __restrict__ cl_out, float* __restrict__ ql) {
    __shared__ SMemS sm;
    int t = threadIdx.x;
    int x = blockIdx.x;

    if (x >= NB_S) {
        // ================= A role (proven structure; 4-chunk sacc to cut LDS) =================
        int b = x - NB_S, Tlo = b * 4;
        scan_ends(na, sm.a.ends, sm.a.wsum, t);
        {
            int tl = t >> 6, l = t & 63;
            const float4* row4 = (const float4*)(si + (size_t)(Tlo + tl) * CS);
            float4 v0 = row4[l];
            float4 v1 = make_float4(0.f, 0.f, 0.f, 0.f);
            if (l < 32) v1 = row4[64 + l];
            float sum = v0.x + v0.y + v0.z + v0.w + v1.x + v1.y + v1.z + v1.w;
            float sq = v0.x*v0.x + v0.y*v0.y + v0.z*v0.z + v0.w*v0.w
                     + v1.x*v1.x + v1.y*v1.y + v1.z*v1.z + v1.w*v1.w;
            #pragma unroll
            for (int m = 32; m >= 1; m >>= 1) { sum += __shfl_xor(sum, m); sq += __shfl_xor(sq, m); }
            float mu = sum * (1.f / CS);
            float rstd = rsqrtf(sq * (1.f / CS) - mu * mu + LN_EPS);
            float4 g0 = ((const float4*)lnw)[l];
            sm.a.xh[4*l+0][tl] = (v0.x - mu) * rstd * g0.x;
            sm.a.xh[4*l+1][tl] = (v0.y - mu) * rstd * g0.y;
            sm.a.xh[4*l+2][tl] = (v0.z - mu) * rstd * g0.z;
            sm.a.xh[4*l+3][tl] = (v0.w - mu) * rstd * g0.w;
            if (l < 32) {
                float4 g1 = ((const float4*)lnw)[64 + l];
                sm.a.xh[256+4*l+0][tl] = (v1.x - mu) * rstd * g1.x;
                sm.a.xh[256+4*l+1][tl] = (v1.y - mu) * rstd * g1.y;
                sm.a.xh[256+4*l+2][tl] = (v1.z - mu) * rstd * g1.z;
                sm.a.xh[256+4*l+3][tl] = (v1.w - mu) * rstd * g1.w;
            }
        }
        __syncthreads();
        if (t < 128) {
            int d4 = t & 31, cc = t >> 5;   // cc in 0..3, 96 channels each
            float4 a0 = make_float4(0,0,0,0), a1 = a0, a2 = a0, a3 = a0;
            const float4* Ws4 = (const float4*)Ws;
            int c0 = 96 * cc;
            #pragma unroll 4
            for (int c = c0; c < c0 + 96; c++) {
                float4 w = Ws4[(size_t)c * 32 + d4];
                float4 xv = *(const float4*)&sm.a.xh[c][0];
                a0.x += xv.x * w.x; a0.y += xv.x * w.y; a0.z += xv.x * w.z; a0.w += xv.x * w.w;
                a1.x += xv.y * w.x; a1.y += xv.y * w.y; a1.z += xv.y * w.z; a1.w += xv.y * w.w;
                a2.x += xv.z * w.x; a2.y += xv.z * w.y; a2.z += xv.z * w.z; a2.w += xv.z * w.w;
                a3.x += xv.w * w.x; a3.y += xv.w * w.y; a3.z += xv.w * w.z; a3.w += xv.w * w.w;
            }
            *(float4*)&sm.a.sacc[cc][0][d4 * 4] = a0;
            *(float4*)&sm.a.sacc[cc][1][d4 * 4] = a1;
            *(float4*)&sm.a.sacc[cc][2][d4 * 4] = a2;
            *(float4*)&sm.a.sacc[cc][3][d4 * 4] = a3;
        }
        __syncthreads();
        if (t < 128) {
            int tk = t >> 5, d = t & 31;
            float4 a = make_float4(0,0,0,0);
            #pragma unroll
            for (int cc = 0; cc < 4; cc++) {
                float4 p = *(const float4*)&sm.a.sacc[cc][tk][d * 4];
                a.x += p.x; a.y += p.y; a.z += p.z; a.w += p.w;
            }
            float4 bb = ((const float4*)bs)[d];
            float m = mask[Tlo + tk];
            a.x = (a.x + bb.x) * m; a.y = (a.y + bb.y) * m;
            a.z = (a.z + bb.z) * m; a.w = (a.w + bb.w) * m;
            *(float4*)&sm.a.s_l[tk][d * 4] = a;
        }
        __syncthreads();
        int elo = (Tlo == 0) ? 0 : sm.a.ends[Tlo - 1];
        int e_0 = sm.a.ends[Tlo], e_1 = sm.a.ends[Tlo + 1], e_2 = sm.a.ends[Tlo + 2];
        int ehi = (b == NB_A - 1) ? N_ATOMS : sm.a.ends[Tlo + 3];
        elo = min(max(elo, 0), N_ATOMS);
        ehi = min(max(ehi, 0), N_ATOMS);
        if (ehi < elo) ehi = elo;
        int items = (ehi - elo) * 32;
        for (int i = t; i < items; i += 256) {
            int a = elo + (i >> 5), d = i & 31;
            int tk = (a >= e_0) + (a >= e_1) + (a >= e_2);
            float4 c4 = ((const float4*)cl)[(size_t)a * 32 + d];
            float4 sv = *(const float4*)&sm.a.s_l[tk][d * 4];
            float4 co;
            co.x = c4.x + sv.x; co.y = c4.y + sv.y; co.z = c4.z + sv.z; co.w = c4.w + sv.w;
            float px = rl[a * 3 + 0], py = rl[a * 3 + 1], pz = rl[a * 3 + 2];
            float4 w0 = ((const float4*)Wr)[d];
            float4 w1 = ((const float4*)Wr)[32 + d];
            float4 w2 = ((const float4*)Wr)[64 + d];
            float4 bb = ((const float4*)br)[d];
            float4 q;
            q.x = co.x + px * w0.x + py * w1.x + pz * w2.x + bb.x;
            q.y = co.y + px * w0.y + py * w1.y + pz * w2.y + bb.y;
            q.z = co.z + px * w0.z + py * w1.z + pz * w2.z + bb.z;
            q.w = co.w + px * w0.w + py * w1.w + pz * w2.w + bb.w;
            ((float4*)cl_out)[(size_t)a * 32 + d] = co;
            ((float4*)ql)[(size_t)a * 32 + d] = q;
        }
        return;
    }

    // ================= stream role: (blk, 4 q-rows) x FULL k -> 32 KB contiguous (R13 proven) =================
    int blk = x >> 3, qo = (x & 7) * 4;

    const int* mp0 = maps_ws + (blk * 4) * MAPSTRIDE;
    if (t < NK) {
        int sg = t >> 5, kl = t & 31;
        sm.s.kmap_l[t] = mp0[sg * MAPSTRIDE + 33 + kl];
    } else if (t < 132) {
        sm.s.uk_l[t - 128] = mp0[(t - 128) * MAPSTRIDE + 0];
    } else if (t < 136) {
        sm.s.vm_l[t - 132] = mp0[(t - 132) * MAPSTRIDE + 65];
    } else if (t < 140) {
        sm.s.qmap_l[t - 136] = mp0[1 + qo + (t - 136)];
    }
    __syncthreads();

    const float4* plm4 = (const float4*)plm;
    const float4* z4 = (const float4*)z_ws;
    float4* out4 = (float4*)plm_out;
    size_t base = ((size_t)(blk * NQ + qo)) * NK * 4;   // f4 index, 2048 f4 span, contiguous

    #pragma unroll
    for (int i = 0; i < 8; i++) {
        int f = t + i * 256;          // 0..2047
        int d4 = f & 3;
        int kk = (f >> 2) & 127;
        int q  = f >> 9;
        int sg = kk >> 5, kl = kk & 31;
        float4 v = plm4[base + f];
        int pidx = sm.s.qmap_l[q] * sm.s.uk_l[sg] + sm.s.kmap_l[kk];
        float4 z = z4[((size_t)(blk * 4 + sg) * MAXP + pidx) * 4 + d4];
        float vd = ((sm.s.vm_l[sg] >> kl) & 1) ? 1.0f : 0.0f;
        v.x += vd * z.x; v.y += vd * z.y; v.z += vd * z.z; v.w += vd * z.w;
        out4[base + f] = v;
    }
}

extern "C" void kernel_launch(void* const* d_in, const int* in_sizes, int n_in,
                              void* d_out, int out_size, void* d_ws, size_t ws_size,
                              hipStream_t stream) {
    (void)in_sizes; (void)n_in; (void)out_size; (void)ws_size;
    const float* token_mask = (const float*)d_in[0];
    const int*   num_atoms  = (const int*)d_in[1];
    const float* cl   = (const float*)d_in[2];
    const float* plm  = (const float*)d_in[3];
    const float* si   = (const float*)d_in[4];
    const float* zij  = (const float*)d_in[5];
    const float* rl   = (const float*)d_in[6];
    const float* ln_s_w = (const float*)d_in[7];
    const float* W_s  = (const float*)d_in[8];
    const float* b_s  = (const float*)d_in[9];
    const float* ln_z_w = (const float*)d_in[10];
    const float* W_z  = (const float*)d_in[11];
    const float* b_z  = (const float*)d_in[12];
    const float* W_r  = (const float*)d_in[13];
    const float* b_r  = (const float*)d_in[14];

    float* out_cl  = (float*)d_out;
    float* out_plm = out_cl + (size_t)N_ATOMS * CATOM;
    float* out_ql  = out_plm + (size_t)NBLK * NQ * NK * CPAIR;

    float* z_ws    = (float*)d_ws;                                   // 512*1024*16 f = 32 MB
    int*   maps_ws = (int*)((char*)d_ws + (size_t)NTILE * MAXP * CPAIR * 4);

    k_pre<<<NTILE, 256, 0, stream>>>(num_atoms, zij, ln_z_w, W_z, b_z, z_ws, maps_ws);
    k_stream<<<NB_S + NB_A, 256, 0, stream>>>(z_ws, maps_ws, plm, out_plm,
                                              num_atoms, si, ln_s_w, W_s, b_s, token_mask,
                                              cl, rl, W_r, b_r, out_cl, out_ql);
}